// Round 11
// baseline (371.888 us; speedup 1.0000x reference)
//
#include <hip/hip_runtime.h>
#include <hip/hip_bf16.h>
#include <math.h>

typedef short bf16x8 __attribute__((ext_vector_type(8)));
typedef float f32x4 __attribute__((ext_vector_type(4)));

#define MFMA_B16(A, B, C) __builtin_amdgcn_mfma_f32_16x16x32_bf16(A, B, C, 0, 0, 0)

#define NBATCH 8
#define CIN 256
#define NPIX 4096
#define L2E 1.4426950408889634f
#define THR2 8.0f   // defer-max threshold in log2 units -> P bounded by 2^8

__device__ __forceinline__ unsigned short f2b(float f) {
    union { float f; unsigned int u; } v;
    v.f = f;
    return (unsigned short)((v.u + 0x7fffu + ((v.u >> 16) & 1u)) >> 16);
}

__device__ __forceinline__ unsigned int cvtpk(float lo, float hi) {
    unsigned int r;
    asm volatile("v_cvt_pk_bf16_f32 %0, %1, %2" : "=v"(r) : "v"(lo), "v"(hi));
    return r;
}

// ---------------------------------------------------------------------------
// Kernel 0: pack weights to bf16 once (kills per-block scalar f2b VALU storm).
// wqk rows 0..15 = Wq * log2(e) (folds exp->exp2), rows 16..31 = Wk.
// ---------------------------------------------------------------------------
__global__ void packw_kernel(const float* __restrict__ Wq, const float* __restrict__ Wk,
                             const float* __restrict__ Wv,
                             unsigned short* __restrict__ wv_bf,
                             unsigned short* __restrict__ wqk_bf) {
    int t = blockIdx.x * 256 + threadIdx.x;      // 288 blocks -> 73728 threads
    if (t < 65536) {
        wv_bf[t] = f2b(Wv[t]);
    } else {
        int u = t - 65536;                        // 0..8191
        int r = u >> 8, c = u & 255;
        float v = (r < 16) ? Wq[r * 256 + c] * L2E : Wk[(r - 16) * 256 + c];
        wqk_bf[u] = f2b(v);
    }
}

// ---------------------------------------------------------------------------
// Kernel A: 1x1-conv QKV projection (weights now bf16 vector loads).
//   qT,kT: [B][N][32] bf16 (d=16..31 zero pad; q pre-scaled by log2e)
//   v: [B][256][N] bf16
// ---------------------------------------------------------------------------
__global__ __launch_bounds__(256, 2) void qkv_kernel(
    const float* __restrict__ x,
    const unsigned short* __restrict__ wv_bf, const unsigned short* __restrict__ wqk_bf,
    const float* __restrict__ bq, const float* __restrict__ bk, const float* __restrict__ bv,
    unsigned short* __restrict__ qT, unsigned short* __restrict__ kT,
    unsigned short* __restrict__ vv)
{
    constexpr int XSTR = 264;
    __shared__ __align__(16) unsigned short xs[64 * XSTR];
    const int b     = blockIdx.x >> 6;
    const int nbase = (blockIdx.x & 63) * 64;
    const int tid = threadIdx.x;
    const int w  = tid >> 6;
    const int l  = tid & 63;
    const int g  = l >> 4;
    const int ln = l & 15;

    // stage x[b][:, nbase..nbase+63] -> xs[n][c] (bf16, transposed)
    {
        const float* xp = x + (size_t)b * CIN * NPIX + nbase + l;
        unsigned short* xsp = xs + l * XSTR + w * 64;
        #pragma unroll
        for (int cc = 0; cc < 32; ++cc) {
            float v0 = xp[(size_t)(w * 64 + 2 * cc)     * NPIX];
            float v1 = xp[(size_t)(w * 64 + 2 * cc + 1) * NPIX];
            unsigned int pk = (unsigned int)f2b(v0) | ((unsigned int)f2b(v1) << 16);
            *(unsigned int*)(xsp + 2 * cc) = pk;
        }
    }
    __syncthreads();

    const f32x4 vzero = {0.f, 0.f, 0.f, 0.f};
    f32x4 acc[4][4];   // [ct][nt]
    f32x4 accq[4];     // [nt]
    #pragma unroll
    for (int i = 0; i < 4; ++i) {
        accq[i] = vzero;
        #pragma unroll
        for (int j = 0; j < 4; ++j) acc[i][j] = vzero;
    }

    for (int ks = 0; ks < 8; ++ks) {
        const int k0 = ks * 32;
        bf16x8 xf[4];
        #pragma unroll
        for (int nt = 0; nt < 4; ++nt)
            xf[nt] = *(const bf16x8*)(xs + (nt * 16 + ln) * XSTR + k0 + g * 8);
        #pragma unroll
        for (int ct = 0; ct < 4; ++ct) {
            const bf16x8 wf = *(const bf16x8*)(wv_bf + (size_t)(w * 64 + ct * 16 + ln) * CIN + k0 + g * 8);
            #pragma unroll
            for (int nt = 0; nt < 4; ++nt)
                acc[ct][nt] = MFMA_B16(wf, xf[nt], acc[ct][nt]);
        }
        if (w < 2) {
            const bf16x8 wfq = *(const bf16x8*)(wqk_bf + (size_t)(w * 16 + ln) * CIN + k0 + g * 8);
            #pragma unroll
            for (int nt = 0; nt < 4; ++nt)
                accq[nt] = MFMA_B16(wfq, xf[nt], accq[nt]);
        }
    }

    #pragma unroll
    for (int ct = 0; ct < 4; ++ct) {
        #pragma unroll
        for (int r = 0; r < 4; ++r) {
            const int c = w * 64 + ct * 16 + g * 4 + r;
            const float bias = bv[c];
            #pragma unroll
            for (int nt = 0; nt < 4; ++nt)
                vv[((size_t)b * CIN + c) * NPIX + nbase + nt * 16 + ln] =
                    f2b(acc[ct][nt][r] + bias);
        }
    }
    if (w < 2) {
        unsigned short* oq = (w == 0 ? qT : kT);
        #pragma unroll
        for (int r = 0; r < 4; ++r) {
            const int d = g * 4 + r;
            const float bi = (w == 0 ? bq[d] * L2E : bk[d]);
            #pragma unroll
            for (int nt = 0; nt < 4; ++nt)
                oq[((size_t)b * NPIX + nbase + nt * 16 + ln) * 32 + d] =
                    f2b(accq[nt][r] + bi);
        }
    } else {
        // zero the d=16..31 pad rows (ws is re-poisoned 0xAA every launch!)
        unsigned short* oq = (w == 2 ? qT : kT);
        unsigned short* p  = oq + ((size_t)b * NPIX + nbase + l) * 32 + 16;
        uint4 z; z.x = 0; z.y = 0; z.z = 0; z.w = 0;
        *(uint4*)p       = z;
        *(uint4*)(p + 8) = z;
    }
}

// ---------------------------------------------------------------------------
// Kernel B: flash attention + residual. BARRIER-FREE, LDS-FREE.
// 4 waves = (wq query-half) x (wc channel-half): 32 queries x 128 channels each;
// every wave computes QK^T for all 64 keys itself (swapped operands).
// P -> PV B-fragment via 8 bpermute + 4 cndmask per (qt,kk). Defer-max THR2.
// ---------------------------------------------------------------------------
__global__ __launch_bounds__(256, 2) void attn_kernel(
    const float* __restrict__ x, const float* __restrict__ gamma_p,
    const unsigned short* __restrict__ qT, const unsigned short* __restrict__ kT,
    const unsigned short* __restrict__ vv, float* __restrict__ out)
{
    const int b     = blockIdx.x & 7;            // XCD-affine: batch -> XCD
    const int qbase = (blockIdx.x >> 3) * 64;
    const int tid = threadIdx.x;
    const int wid = tid >> 6;
    const int wq  = wid & 1;                     // query half (32 q)
    const int wc  = wid >> 1;                    // channel half (128 ch)
    const int l   = tid & 63;
    const int ln  = l & 15;
    const int g   = l >> 4;
    const float gamma = *gamma_p;

    const int srcA = ln + ((g & 1) << 5);
    const int srcB = srcA + 16;
    const bool hi  = (g >> 1) != 0;

    bf16x8 qf[2];
    #pragma unroll
    for (int qt = 0; qt < 2; ++qt)
        qf[qt] = *(const bf16x8*)(qT + ((size_t)b * NPIX + qbase + wq * 32 + qt * 16 + ln) * 32 + g * 8);

    const f32x4 vzero = {0.f, 0.f, 0.f, 0.f};
    f32x4 acc[2][8];
    #pragma unroll
    for (int i = 0; i < 2; ++i)
        #pragma unroll
        for (int j = 0; j < 8; ++j) acc[i][j] = vzero;
    float m_run[2]  = {-INFINITY, -INFINITY};
    float l_part[2] = {0.f, 0.f};

    const unsigned short* kbase = kT + (size_t)b * NPIX * 32;
    const unsigned short* vbase = vv + ((size_t)b * CIN + wc * 128) * NPIX;

    for (int kt = 0; kt < 64; ++kt) {
        const int k0 = kt * 64;
        bf16x8 kf[4];
        #pragma unroll
        for (int ws = 0; ws < 4; ++ws)
            kf[ws] = *(const bf16x8*)(kbase + (size_t)(k0 + 16 * ws + ln) * 32 + g * 8);

        f32x4 s[2][4];
        #pragma unroll
        for (int qt = 0; qt < 2; ++qt)
            #pragma unroll
            for (int ws = 0; ws < 4; ++ws)
                s[qt][ws] = MFMA_B16(kf[ws], qf[qt], vzero);

        unsigned int pk[2][4][2];
        #pragma unroll
        for (int qt = 0; qt < 2; ++qt) {
            float pml = fmaxf(fmaxf(s[qt][0][0], s[qt][0][1]), fmaxf(s[qt][0][2], s[qt][0][3]));
            #pragma unroll
            for (int ws = 1; ws < 4; ++ws)
                pml = fmaxf(pml, fmaxf(fmaxf(s[qt][ws][0], s[qt][ws][1]),
                                       fmaxf(s[qt][ws][2], s[qt][ws][3])));
            if (__any(pml > m_run[qt] + THR2)) {
                float pm = fmaxf(pml, __shfl_xor(pml, 16));
                pm = fmaxf(pm, __shfl_xor(pm, 32));
                float mn = fmaxf(m_run[qt], pm);
                float sc = exp2f(m_run[qt] - mn);
                #pragma unroll
                for (int ct = 0; ct < 8; ++ct) acc[qt][ct] *= sc;
                l_part[qt] *= sc;
                m_run[qt] = mn;
            }
            float ts = 0.f;
            #pragma unroll
            for (int ws = 0; ws < 4; ++ws)
                #pragma unroll
                for (int r = 0; r < 4; ++r) {
                    float p = exp2f(s[qt][ws][r] - m_run[qt]);
                    s[qt][ws][r] = p;
                    ts += p;
                }
            l_part[qt] += ts;
            #pragma unroll
            for (int ws = 0; ws < 4; ++ws) {
                pk[qt][ws][0] = cvtpk(s[qt][ws][0], s[qt][ws][1]);
                pk[qt][ws][1] = cvtpk(s[qt][ws][2], s[qt][ws][3]);
            }
        }

        #pragma unroll
        for (int kk = 0; kk < 2; ++kk) {
            bf16x8 pf[2];
            #pragma unroll
            for (int qt = 0; qt < 2; ++qt) {
                unsigned int aL0 = __shfl((int)pk[qt][2 * kk][0],     srcA);
                unsigned int aL1 = __shfl((int)pk[qt][2 * kk][1],     srcA);
                unsigned int aH0 = __shfl((int)pk[qt][2 * kk + 1][0], srcA);
                unsigned int aH1 = __shfl((int)pk[qt][2 * kk + 1][1], srcA);
                unsigned int bL0 = __shfl((int)pk[qt][2 * kk][0],     srcB);
                unsigned int bL1 = __shfl((int)pk[qt][2 * kk][1],     srcB);
                unsigned int bH0 = __shfl((int)pk[qt][2 * kk + 1][0], srcB);
                unsigned int bH1 = __shfl((int)pk[qt][2 * kk + 1][1], srcB);
                union { unsigned int u[4]; bf16x8 v; } pu;
                pu.u[0] = hi ? aH0 : aL0;
                pu.u[1] = hi ? aH1 : aL1;
                pu.u[2] = hi ? bH0 : bL0;
                pu.u[3] = hi ? bH1 : bL1;
                pf[qt] = pu.v;
            }
            __builtin_amdgcn_s_setprio(1);
            #pragma unroll
            for (int ct = 0; ct < 8; ++ct) {
                const bf16x8 vf = *(const bf16x8*)(
                    vbase + (size_t)(ct * 16 + ln) * NPIX + k0 + kk * 32 + g * 8);
                acc[0][ct] = MFMA_B16(vf, pf[0], acc[0][ct]);
                acc[1][ct] = MFMA_B16(vf, pf[1], acc[1][ct]);
            }
            __builtin_amdgcn_s_setprio(0);
        }
    }

    // epilogue: reduce l across g-lanes, y = acc/l, out = x + gamma*y
    #pragma unroll
    for (int qt = 0; qt < 2; ++qt) {
        float lt = l_part[qt];
        lt += __shfl_xor(lt, 16);
        lt += __shfl_xor(lt, 32);
        const float inv = 1.0f / lt;
        const int n = qbase + wq * 32 + qt * 16 + ln;
        #pragma unroll
        for (int ct = 0; ct < 8; ++ct) {
            #pragma unroll
            for (int r = 0; r < 4; ++r) {
                const int c = wc * 128 + ct * 16 + g * 4 + r;
                const size_t idx = ((size_t)b * CIN + c) * NPIX + n;
                out[idx] = x[idx] + gamma * (acc[qt][ct][r] * inv);
            }
        }
    }
}

extern "C" void kernel_launch(void* const* d_in, const int* in_sizes, int n_in,
                              void* d_out, int out_size, void* d_ws, size_t ws_size,
                              hipStream_t stream) {
    const float* x     = (const float*)d_in[0];
    const float* Wq    = (const float*)d_in[1];
    const float* bq    = (const float*)d_in[2];
    const float* Wk    = (const float*)d_in[3];
    const float* bk    = (const float*)d_in[4];
    const float* Wv    = (const float*)d_in[5];
    const float* bv    = (const float*)d_in[6];
    const float* gamma = (const float*)d_in[7];

    // ws layout (bf16): qT 2MB | kT 2MB | v 16MB | wv_bf 128KB | wqk_bf 16KB
    unsigned short* qTp  = (unsigned short*)d_ws;
    unsigned short* kTp  = qTp + (size_t)NBATCH * NPIX * 32;
    unsigned short* vvp  = kTp + (size_t)NBATCH * NPIX * 32;
    unsigned short* wvb  = vvp + (size_t)NBATCH * CIN * NPIX;
    unsigned short* wqkb = wvb + 256 * 256;

    packw_kernel<<<288, 256, 0, stream>>>(Wq, Wk, Wv, wvb, wqkb);
    qkv_kernel<<<512, 256, 0, stream>>>(x, wvb, wqkb, bq, bk, bv, qTp, kTp, vvp);
    attn_kernel<<<512, 256, 0, stream>>>(x, gamma, qTp, kTp, vvp, (float*)d_out);
}